// Round 1
// 419.192 us; speedup vs baseline: 1.1404x; 1.1404x over previous
//
#include <hip/hip_runtime.h>
#include <hip/hip_bf16.h>

#define VOCAB 32000
#define NUM_CLASS 16
#define HID 256
#define KCAT 512          // concat(e, h) K dimension
#define BATCH 2048

typedef __attribute__((ext_vector_type(8))) __bf16 bf16x8;
typedef __attribute__((ext_vector_type(4))) float floatx4;

// RNE f32 -> bf16 (finite inputs)
__device__ __forceinline__ unsigned short f32_to_bf16_u16(float f) {
    union { float f; unsigned u; } a;
    a.f = f;
    unsigned r = a.u + 0x7fffu + ((a.u >> 16) & 1u);
    return (unsigned short)(r >> 16);
}

struct bf8v { unsigned short s[8]; };

// async global->LDS, 16B per lane. LDS dest is wave-uniform base + lane*16.
__device__ __forceinline__ void lds_load16(unsigned short* lds, const unsigned short* g) {
    __builtin_amdgcn_global_load_lds(
        (const __attribute__((address_space(1))) unsigned int*)g,
        (__attribute__((address_space(3))) unsigned int*)lds, 16, 0, 0);
}

// ---------------------------------------------------------------------------
// Bucket batch elements by class: perm[bases[g] .. bases[g]+counts[g]) = c's
// with z[c]==g. Single block; order within a class is irrelevant.
// ---------------------------------------------------------------------------
__global__ __launch_bounds__(256) void bucket_kernel(
    const int* __restrict__ z, int* __restrict__ perm,
    int* __restrict__ counts, int* __restrict__ bases)
{
    __shared__ int s_cnt[NUM_CLASS];
    __shared__ int s_off[NUM_CLASS];
    const int t = threadIdx.x;
    if (t < NUM_CLASS) s_cnt[t] = 0;
    __syncthreads();
    for (int c = t; c < BATCH; c += 256) atomicAdd(&s_cnt[z[c]], 1);
    __syncthreads();
    if (t == 0) {
        int acc = 0;
        for (int i = 0; i < NUM_CLASS; ++i) { s_off[i] = acc; acc += s_cnt[i]; }
    }
    __syncthreads();
    if (t < NUM_CLASS) { counts[t] = s_cnt[t]; bases[t] = s_off[t]; }
    __syncthreads();
    for (int c = t; c < BATCH; c += 256) {
        int p = atomicAdd(&s_off[z[c]], 1);
        perm[p] = c;
    }
}

// ---------------------------------------------------------------------------
// Fused prep: one kernel does all three f32->bf16 staging jobs.
//   range 0: G[c] = [bf16(E[x[c]]), bf16(h[c])]          (BATCH x KCAT)
//   range 1: Bcat[g][k] = [bf16(W[g][k]), bf16(U[g][k])] (NUM_CLASS*HID x KCAT)
//   range 2: Vw_bf = bf16(Vw)                            (VOCAB x HID)
// Every work item: load 2x float4, convert 8, store 16B. Exact grid, no guard.
// ---------------------------------------------------------------------------
#define PREP_G   (BATCH * KCAT / 8)              // 131072
#define PREP_WU  (NUM_CLASS * HID * KCAT / 8)    // 262144
#define PREP_VW  (VOCAB * HID / 8)               // 1024000
#define PREP_TOT (PREP_G + PREP_WU + PREP_VW)    // 1417216 = 5536 * 256

__global__ __launch_bounds__(256) void prep_kernel(
    const int* __restrict__ x, const float* __restrict__ E,
    const float* __restrict__ h,
    const float* __restrict__ W, const float* __restrict__ U,
    const float* __restrict__ Vw,
    unsigned short* __restrict__ G, unsigned short* __restrict__ Bcat,
    unsigned short* __restrict__ Vw_bf)
{
    const int tid = blockIdx.x * 256 + threadIdx.x;
    const float* src;
    unsigned short* dst;
    if (tid < PREP_G) {
        const int c  = tid >> 6;              // 64 chunks of 8 per row
        const int j0 = (tid & 63) * 8;
        src = (j0 < HID) ? (E + (size_t)x[c] * HID + j0)
                         : (h + (size_t)c * HID + (j0 - HID));
        dst = G + (size_t)c * KCAT + j0;
    } else if (tid < PREP_G + PREP_WU) {
        const int idx = tid - PREP_G;
        const int row = idx >> 6;             // g*HID + k
        const int j0  = (idx & 63) * 8;
        src = (j0 < HID) ? (W + (size_t)row * HID + j0)
                         : (U + (size_t)row * HID + (j0 - HID));
        dst = Bcat + (size_t)row * KCAT + j0;
    } else {
        const int idx = tid - (PREP_G + PREP_WU);
        src = Vw + (size_t)idx * 8;
        dst = Vw_bf + (size_t)idx * 8;
    }
    float4 v0 = ((const float4*)src)[0];
    float4 v1 = ((const float4*)src)[1];
    bf8v o;
    o.s[0] = f32_to_bf16_u16(v0.x); o.s[1] = f32_to_bf16_u16(v0.y);
    o.s[2] = f32_to_bf16_u16(v0.z); o.s[3] = f32_to_bf16_u16(v0.w);
    o.s[4] = f32_to_bf16_u16(v1.x); o.s[5] = f32_to_bf16_u16(v1.y);
    o.s[6] = f32_to_bf16_u16(v1.z); o.s[7] = f32_to_bf16_u16(v1.w);
    *(bf8v*)dst = o;
}

// ---------------------------------------------------------------------------
// Stage 1 as per-class GEMM: for class g, rows c in bucket:
//   ht[c][k] = tanh( G[c][:] . Bcat[g][k][:] )   (K = 512)
// Grid: (m_tile, class). Block 256 thr = 4 waves; tile M=32, N=256 (HID).
// ---------------------------------------------------------------------------
__global__ __launch_bounds__(256) void rnn_gemm_kernel(
    const unsigned short* __restrict__ G,     // BATCH x KCAT
    const unsigned short* __restrict__ Bcat,  // NUM_CLASS x HID x KCAT
    const int* __restrict__ perm, const int* __restrict__ counts,
    const int* __restrict__ bases,
    float* __restrict__ ht_f32, unsigned short* __restrict__ ht_bf16)
{
    const int g = blockIdx.y;
    const int cnt = counts[g];
    const int mstart = blockIdx.x * 32;
    if (mstart >= cnt) return;
    const int base = bases[g];

    __shared__ int s_rows[32];
    if (threadIdx.x < 32) {
        int mi = mstart + threadIdx.x;
        s_rows[threadIdx.x] = perm[base + (mi < cnt ? mi : cnt - 1)];
    }
    __syncthreads();

    const int lane = threadIdx.x & 63;
    const int wave = threadIdx.x >> 6;
    const int n0   = wave * 64;
    const int lrow = lane & 15;
    const int quad = lane >> 4;
    const int kq   = quad * 8;

    const unsigned short* Bg = Bcat + (size_t)g * HID * KCAT;

    floatx4 acc[2][4] = {};
#pragma unroll 4
    for (int k0 = 0; k0 < KCAT; k0 += 32) {
        bf16x8 a[2], b[4];
#pragma unroll
        for (int mi = 0; mi < 2; ++mi) {
            const int row = s_rows[mi * 16 + lrow];
            a[mi] = *(const bf16x8*)(G + (size_t)row * KCAT + k0 + kq);
        }
#pragma unroll
        for (int ni = 0; ni < 4; ++ni)
            b[ni] = *(const bf16x8*)(Bg + (size_t)(n0 + ni * 16 + lrow) * KCAT + k0 + kq);
#pragma unroll
        for (int mi = 0; mi < 2; ++mi)
#pragma unroll
            for (int ni = 0; ni < 4; ++ni)
                acc[mi][ni] = __builtin_amdgcn_mfma_f32_16x16x32_bf16(
                    a[mi], b[ni], acc[mi][ni], 0, 0, 0);
    }

#pragma unroll
    for (int mi = 0; mi < 2; ++mi) {
#pragma unroll
        for (int r = 0; r < 4; ++r) {
            const int midx = mi * 16 + quad * 4 + r;
            if (mstart + midx >= cnt) continue;
            const int c = s_rows[midx];
#pragma unroll
            for (int ni = 0; ni < 4; ++ni) {
                const int k = n0 + ni * 16 + lrow;
                const float v = tanhf(acc[mi][ni][r]);
                ht_f32 [(size_t)c * HID + k] = v;
                ht_bf16[(size_t)c * HID + k] = f32_to_bf16_u16(v);
            }
        }
    }
}

// ---------------------------------------------------------------------------
// Stage 2: logits = ht . Vw^T + Vb   (M=2048, N=32000, K=256)
// m97 structure: 128x128 tile, BK=64, global_load_lds(16B) staging with
// both-sides XOR chunk swizzle (free 2-way bank access), 4 waves (2x2),
// XCD-aware n-major block swizzle, nontemporal C stores.
// ---------------------------------------------------------------------------
__global__ __launch_bounds__(256) void out_gemm_kernel(
    const unsigned short* __restrict__ A,   // ht bf16, 2048 x 256
    const unsigned short* __restrict__ B,   // Vw bf16, 32000 x 256
    const float* __restrict__ Vb,
    float* __restrict__ C)                  // 2048 x 32000
{
    __shared__ unsigned short sA[128 * 64]; // tile rows x BK, 128B rows, 8 chunks
    __shared__ unsigned short sB[128 * 64];

    // bijective XCD swizzle (4000 = 8 * 500), n-major within an XCD chunk:
    // each XCD sees ~31 B-panels (2 MB, L2-resident) x all 16 M-blocks.
    const int id  = blockIdx.x;
    const int sid = (id & 7) * 500 + (id >> 3);
    const int n0  = (sid >> 4) * 128;       // 250 n-panels
    const int m0  = (sid & 15) * 128;       // 16 m-panels

    const int lane = threadIdx.x & 63;
    const int wave = threadIdx.x >> 6;
    const int wr = wave >> 1, wc = wave & 1;
    const int lrow = lane & 15;
    const int quad = lane >> 4;

    // staging geometry: wave-load wl covers tile rows [wl*8, wl*8+8).
    // LDS slot (r, s) holds global chunk d = s ^ (r&7); HW writes lane l to
    // slot (wl*8 + l>>3, l&7), so the global source chunk is pre-swizzled.
    const int srow   = lane >> 3;           // row within wave-load
    const int schunk = (lane & 7) ^ srow;   // inverse-swizzled global chunk

    floatx4 acc[4][4] = {};

#pragma unroll
    for (int kt = 0; kt < 4; ++kt) {
        const int k0 = kt * 64;
        __syncthreads();                    // previous tile's reads complete
#pragma unroll
        for (int it = 0; it < 4; ++it) {
            const int wl = wave * 4 + it;
            const int r  = wl * 8 + srow;
            lds_load16(&sA[wl * 512], A + (size_t)(m0 + r) * HID + k0 + schunk * 8);
            lds_load16(&sB[wl * 512], B + (size_t)(n0 + r) * HID + k0 + schunk * 8);
        }
        __syncthreads();                    // compiler drains vmcnt before barrier

#pragma unroll
        for (int ks = 0; ks < 2; ++ks) {
            bf16x8 a[4], b[4];
#pragma unroll
            for (int mi = 0; mi < 4; ++mi) {
                const int ra = wr * 64 + mi * 16 + lrow;
                const int s  = (ks * 4 + quad) ^ (ra & 7);
                a[mi] = *(const bf16x8*)&sA[ra * 64 + s * 8];
            }
#pragma unroll
            for (int ni = 0; ni < 4; ++ni) {
                const int rb = wc * 64 + ni * 16 + lrow;
                const int s  = (ks * 4 + quad) ^ (rb & 7);
                b[ni] = *(const bf16x8*)&sB[rb * 64 + s * 8];
            }
#pragma unroll
            for (int mi = 0; mi < 4; ++mi)
#pragma unroll
                for (int ni = 0; ni < 4; ++ni)
                    acc[mi][ni] = __builtin_amdgcn_mfma_f32_16x16x32_bf16(
                        a[mi], b[ni], acc[mi][ni], 0, 0, 0);
        }
    }

    const int m_wave = m0 + wr * 64;
    const int n_wave = n0 + wc * 64;
    const int row_q  = quad * 4;
#pragma unroll
    for (int ni = 0; ni < 4; ++ni) {
        const int col = n_wave + ni * 16 + lrow;
        const float vb = Vb[col];
#pragma unroll
        for (int mi = 0; mi < 4; ++mi) {
            float* cp = C + (size_t)(m_wave + mi * 16 + row_q) * VOCAB + col;
#pragma unroll
            for (int r = 0; r < 4; ++r)
                __builtin_nontemporal_store(acc[mi][ni][r] + vb, cp + (size_t)r * VOCAB);
        }
    }
}

extern "C" void kernel_launch(void* const* d_in, const int* in_sizes, int n_in,
                              void* d_out, int out_size, void* d_ws, size_t ws_size,
                              hipStream_t stream) {
    const int*   x  = (const int*)d_in[0];
    const int*   z  = (const int*)d_in[1];
    const float* h  = (const float*)d_in[2];
    const float* E  = (const float*)d_in[3];
    const float* Vw = (const float*)d_in[4];
    const float* Vb = (const float*)d_in[5];
    const float* W  = (const float*)d_in[6];
    const float* U  = (const float*)d_in[7];

    float* logits = (float*)d_out;
    float* ht_out = logits + (size_t)BATCH * VOCAB;

    // workspace layout
    char* p = (char*)d_ws;
    unsigned short* Vw_bf = (unsigned short*)p;  p += (size_t)VOCAB * HID * 2;
    unsigned short* ht_bf = (unsigned short*)p;  p += (size_t)BATCH * HID * 2;
    unsigned short* G     = (unsigned short*)p;  p += (size_t)BATCH * KCAT * 2;
    unsigned short* Bcat  = (unsigned short*)p;  p += (size_t)NUM_CLASS * HID * KCAT * 2;
    int* perm   = (int*)p;  p += BATCH * 4;
    int* counts = (int*)p;  p += NUM_CLASS * 4;
    int* bases  = (int*)p;  p += NUM_CLASS * 4;

    bucket_kernel<<<1, 256, 0, stream>>>(z, perm, counts, bases);
    prep_kernel<<<PREP_TOT / 256, 256, 0, stream>>>(x, E, h, W, U, Vw, G, Bcat, Vw_bf);
    rnn_gemm_kernel<<<dim3(BATCH / 32, NUM_CLASS), 256, 0, stream>>>(
        G, Bcat, perm, counts, bases, ht_out, ht_bf);
    out_gemm_kernel<<<4000, 256, 0, stream>>>(ht_bf, Vw_bf, Vb, logits);
}

// Round 2
// 412.819 us; speedup vs baseline: 1.1580x; 1.0154x over previous
//
#include <hip/hip_runtime.h>
#include <hip/hip_bf16.h>

#define VOCAB 32000
#define NUM_CLASS 16
#define HID 256
#define KCAT 512          // concat(e, h) K dimension
#define BATCH 2048

typedef __attribute__((ext_vector_type(8))) __bf16 bf16x8;
typedef __attribute__((ext_vector_type(4))) float floatx4;

// RNE f32 -> bf16 (finite inputs)
__device__ __forceinline__ unsigned short f32_to_bf16_u16(float f) {
    union { float f; unsigned u; } a;
    a.f = f;
    unsigned r = a.u + 0x7fffu + ((a.u >> 16) & 1u);
    return (unsigned short)(r >> 16);
}

struct bf8v { unsigned short s[8]; };

// async global->LDS, 16B per lane. LDS dest is wave-uniform base + lane*16.
__device__ __forceinline__ void lds_load16(unsigned short* lds, const unsigned short* g) {
    __builtin_amdgcn_global_load_lds(
        (const __attribute__((address_space(1))) unsigned int*)g,
        (__attribute__((address_space(3))) unsigned int*)lds, 16, 0, 0);
}

// ---------------------------------------------------------------------------
// Fused prep + bucket.
// Blocks 0..5535: f32->bf16 staging (G, Bcat, Vw_bf).
// Block 5536: bucket batch elements by class into perm/counts/bases.
// Bucketing is a single block (~4 us) that previously serialized on the
// stream; here it hides under the 5536 prep blocks.
// ---------------------------------------------------------------------------
#define PREP_G   (BATCH * KCAT / 8)              // 131072
#define PREP_WU  (NUM_CLASS * HID * KCAT / 8)    // 262144
#define PREP_VW  (VOCAB * HID / 8)               // 1024000
#define PREP_TOT (PREP_G + PREP_WU + PREP_VW)    // 1417216 = 5536 * 256
#define PREP_BLOCKS (PREP_TOT / 256)             // 5536

__global__ __launch_bounds__(256) void prep_bucket_kernel(
    const int* __restrict__ x, const float* __restrict__ E,
    const float* __restrict__ h,
    const float* __restrict__ W, const float* __restrict__ U,
    const float* __restrict__ Vw, const int* __restrict__ z,
    unsigned short* __restrict__ G, unsigned short* __restrict__ Bcat,
    unsigned short* __restrict__ Vw_bf,
    int* __restrict__ perm, int* __restrict__ counts, int* __restrict__ bases)
{
    if (blockIdx.x == PREP_BLOCKS) {
        // ---- bucket ----
        __shared__ int s_cnt[NUM_CLASS];
        __shared__ int s_off[NUM_CLASS];
        const int t = threadIdx.x;
        if (t < NUM_CLASS) s_cnt[t] = 0;
        __syncthreads();
        for (int c = t; c < BATCH; c += 256) atomicAdd(&s_cnt[z[c]], 1);
        __syncthreads();
        if (t == 0) {
            int acc = 0;
            for (int i = 0; i < NUM_CLASS; ++i) { s_off[i] = acc; acc += s_cnt[i]; }
        }
        __syncthreads();
        if (t < NUM_CLASS) { counts[t] = s_cnt[t]; bases[t] = s_off[t]; }
        __syncthreads();
        for (int c = t; c < BATCH; c += 256) {
            int p = atomicAdd(&s_off[z[c]], 1);
            perm[p] = c;
        }
        return;
    }

    // ---- prep: load 2x float4, convert 8, store 16B ----
    const int tid = blockIdx.x * 256 + threadIdx.x;
    const float* src;
    unsigned short* dst;
    if (tid < PREP_G) {
        const int c  = tid >> 6;              // 64 chunks of 8 per row
        const int j0 = (tid & 63) * 8;
        src = (j0 < HID) ? (E + (size_t)x[c] * HID + j0)
                         : (h + (size_t)c * HID + (j0 - HID));
        dst = G + (size_t)c * KCAT + j0;
    } else if (tid < PREP_G + PREP_WU) {
        const int idx = tid - PREP_G;
        const int row = idx >> 6;             // g*HID + k
        const int j0  = (idx & 63) * 8;
        src = (j0 < HID) ? (W + (size_t)row * HID + j0)
                         : (U + (size_t)row * HID + (j0 - HID));
        dst = Bcat + (size_t)row * KCAT + j0;
    } else {
        const int idx = tid - (PREP_G + PREP_WU);
        src = Vw + (size_t)idx * 8;
        dst = Vw_bf + (size_t)idx * 8;
    }
    float4 v0 = ((const float4*)src)[0];
    float4 v1 = ((const float4*)src)[1];
    bf8v o;
    o.s[0] = f32_to_bf16_u16(v0.x); o.s[1] = f32_to_bf16_u16(v0.y);
    o.s[2] = f32_to_bf16_u16(v0.z); o.s[3] = f32_to_bf16_u16(v0.w);
    o.s[4] = f32_to_bf16_u16(v1.x); o.s[5] = f32_to_bf16_u16(v1.y);
    o.s[6] = f32_to_bf16_u16(v1.z); o.s[7] = f32_to_bf16_u16(v1.w);
    *(bf8v*)dst = o;
}

// ---------------------------------------------------------------------------
// Stage 1 as per-class GEMM: for class g, rows c in bucket:
//   ht[c][k] = tanh( G[c][:] . Bcat[g][k][:] )   (K = 512)
// Grid: (m_tile, class). Block 256 thr = 4 waves; tile M=32, N=256 (HID).
// ---------------------------------------------------------------------------
__global__ __launch_bounds__(256) void rnn_gemm_kernel(
    const unsigned short* __restrict__ G,     // BATCH x KCAT
    const unsigned short* __restrict__ Bcat,  // NUM_CLASS x HID x KCAT
    const int* __restrict__ perm, const int* __restrict__ counts,
    const int* __restrict__ bases,
    float* __restrict__ ht_f32, unsigned short* __restrict__ ht_bf16)
{
    const int g = blockIdx.y;
    const int cnt = counts[g];
    const int mstart = blockIdx.x * 32;
    if (mstart >= cnt) return;
    const int base = bases[g];

    __shared__ int s_rows[32];
    if (threadIdx.x < 32) {
        int mi = mstart + threadIdx.x;
        s_rows[threadIdx.x] = perm[base + (mi < cnt ? mi : cnt - 1)];
    }
    __syncthreads();

    const int lane = threadIdx.x & 63;
    const int wave = threadIdx.x >> 6;
    const int n0   = wave * 64;
    const int lrow = lane & 15;
    const int quad = lane >> 4;
    const int kq   = quad * 8;

    const unsigned short* Bg = Bcat + (size_t)g * HID * KCAT;

    floatx4 acc[2][4] = {};
#pragma unroll 4
    for (int k0 = 0; k0 < KCAT; k0 += 32) {
        bf16x8 a[2], b[4];
#pragma unroll
        for (int mi = 0; mi < 2; ++mi) {
            const int row = s_rows[mi * 16 + lrow];
            a[mi] = *(const bf16x8*)(G + (size_t)row * KCAT + k0 + kq);
        }
#pragma unroll
        for (int ni = 0; ni < 4; ++ni)
            b[ni] = *(const bf16x8*)(Bg + (size_t)(n0 + ni * 16 + lrow) * KCAT + k0 + kq);
#pragma unroll
        for (int mi = 0; mi < 2; ++mi)
#pragma unroll
            for (int ni = 0; ni < 4; ++ni)
                acc[mi][ni] = __builtin_amdgcn_mfma_f32_16x16x32_bf16(
                    a[mi], b[ni], acc[mi][ni], 0, 0, 0);
    }

#pragma unroll
    for (int mi = 0; mi < 2; ++mi) {
#pragma unroll
        for (int r = 0; r < 4; ++r) {
            const int midx = mi * 16 + quad * 4 + r;
            if (mstart + midx >= cnt) continue;
            const int c = s_rows[midx];
#pragma unroll
            for (int ni = 0; ni < 4; ++ni) {
                const int k = n0 + ni * 16 + lrow;
                const float v = tanhf(acc[mi][ni][r]);
                ht_f32 [(size_t)c * HID + k] = v;
                ht_bf16[(size_t)c * HID + k] = f32_to_bf16_u16(v);
            }
        }
    }
}

// ---------------------------------------------------------------------------
// Stage 2: logits = ht . Vw^T + Vb   (M=2048, N=32000, K=256)
// 128x128 tile, BK=32, DOUBLE-BUFFERED global_load_lds staging (T3 minimum
// 2-phase recipe): stage(t+1) issued before compute(t), one barrier per
// tile -> staged-load latency hides under ds_read+MFMA. LDS stays 32 KB
// (same occupancy as single-buffer BK=64).
// Swizzle (both-sides): LDS slot (r,s) holds global chunk s ^ ((r>>1)&3);
// read pattern then hits each bank 2-way (free).
// ---------------------------------------------------------------------------
__global__ __launch_bounds__(256) void out_gemm_kernel(
    const unsigned short* __restrict__ A,   // ht bf16, 2048 x 256
    const unsigned short* __restrict__ B,   // Vw bf16, 32000 x 256
    const float* __restrict__ Vb,
    float* __restrict__ C)                  // 2048 x 32000
{
    __shared__ unsigned short sA[2][128 * 32];  // 8 KB per buffer
    __shared__ unsigned short sB[2][128 * 32];

    // bijective XCD swizzle (4000 = 8 * 500), n-major within an XCD chunk:
    // each XCD sees ~31 B-panels (2 MB, L2-resident) x all 16 M-blocks.
    const int id  = blockIdx.x;
    const int sid = (id & 7) * 500 + (id >> 3);
    const int n0  = (sid >> 4) * 128;       // 250 n-panels
    const int m0  = (sid & 15) * 128;       // 16 m-panels

    const int lane = threadIdx.x & 63;
    const int wave = threadIdx.x >> 6;
    const int wr = wave >> 1, wc = wave & 1;
    const int lrow = lane & 15;
    const int quad = lane >> 4;

    // staging: wave-load wl covers tile rows [wl*16, wl*16+16), 4 chunks/row.
    // HW writes lane l to slot (wl*16 + l>>2, l&3); source chunk pre-swizzled
    // so slot (r,s) holds global chunk s ^ ((r>>1)&3).
    const int srow   = lane >> 2;                       // row within wave-load
    const int schunk = (lane & 3) ^ ((lane >> 3) & 3);  // inverse-swizzled

    // read-side swizzled chunk slot: s = quad ^ ((ra>>1)&3); for ra =
    // (64|16)-multiples + lrow this reduces to quad ^ ((lrow>>1)&3).
    const int rslot = quad ^ ((lrow >> 1) & 3);

    floatx4 acc[4][4] = {};

    // prologue: stage tile 0
#pragma unroll
    for (int it = 0; it < 2; ++it) {
        const int wl = wave * 2 + it;
        const int r  = wl * 16 + srow;
        lds_load16(&sA[0][wl * 512], A + (size_t)(m0 + r) * HID + schunk * 8);
        lds_load16(&sB[0][wl * 512], B + (size_t)(n0 + r) * HID + schunk * 8);
    }
    __syncthreads();

#pragma unroll
    for (int kt = 0; kt < 8; ++kt) {
        const int cur = kt & 1;
        if (kt < 7) {
            const int k0n = (kt + 1) * 32;
#pragma unroll
            for (int it = 0; it < 2; ++it) {
                const int wl = wave * 2 + it;
                const int r  = wl * 16 + srow;
                lds_load16(&sA[cur ^ 1][wl * 512],
                           A + (size_t)(m0 + r) * HID + k0n + schunk * 8);
                lds_load16(&sB[cur ^ 1][wl * 512],
                           B + (size_t)(n0 + r) * HID + k0n + schunk * 8);
            }
        }

        bf16x8 a[4], b[4];
#pragma unroll
        for (int mi = 0; mi < 4; ++mi) {
            const int ra = wr * 64 + mi * 16 + lrow;
            a[mi] = *(const bf16x8*)&sA[cur][ra * 32 + rslot * 8];
        }
#pragma unroll
        for (int ni = 0; ni < 4; ++ni) {
            const int rb = wc * 64 + ni * 16 + lrow;
            b[ni] = *(const bf16x8*)&sB[cur][rb * 32 + rslot * 8];
        }
#pragma unroll
        for (int mi = 0; mi < 4; ++mi)
#pragma unroll
            for (int ni = 0; ni < 4; ++ni)
                acc[mi][ni] = __builtin_amdgcn_mfma_f32_16x16x32_bf16(
                    a[mi], b[ni], acc[mi][ni], 0, 0, 0);

        __syncthreads();   // drains vmcnt (next tile staged) + lgkm (reads done)
    }

    const int m_wave = m0 + wr * 64;
    const int n_wave = n0 + wc * 64;
    const int row_q  = quad * 4;
#pragma unroll
    for (int ni = 0; ni < 4; ++ni) {
        const int col = n_wave + ni * 16 + lrow;
        const float vb = Vb[col];
#pragma unroll
        for (int mi = 0; mi < 4; ++mi) {
            float* cp = C + (size_t)(m_wave + mi * 16 + row_q) * VOCAB + col;
#pragma unroll
            for (int r = 0; r < 4; ++r)
                __builtin_nontemporal_store(acc[mi][ni][r] + vb, cp + (size_t)r * VOCAB);
        }
    }
}

extern "C" void kernel_launch(void* const* d_in, const int* in_sizes, int n_in,
                              void* d_out, int out_size, void* d_ws, size_t ws_size,
                              hipStream_t stream) {
    const int*   x  = (const int*)d_in[0];
    const int*   z  = (const int*)d_in[1];
    const float* h  = (const float*)d_in[2];
    const float* E  = (const float*)d_in[3];
    const float* Vw = (const float*)d_in[4];
    const float* Vb = (const float*)d_in[5];
    const float* W  = (const float*)d_in[6];
    const float* U  = (const float*)d_in[7];

    float* logits = (float*)d_out;
    float* ht_out = logits + (size_t)BATCH * VOCAB;

    // workspace layout
    char* p = (char*)d_ws;
    unsigned short* Vw_bf = (unsigned short*)p;  p += (size_t)VOCAB * HID * 2;
    unsigned short* ht_bf = (unsigned short*)p;  p += (size_t)BATCH * HID * 2;
    unsigned short* G     = (unsigned short*)p;  p += (size_t)BATCH * KCAT * 2;
    unsigned short* Bcat  = (unsigned short*)p;  p += (size_t)NUM_CLASS * HID * KCAT * 2;
    int* perm   = (int*)p;  p += BATCH * 4;
    int* counts = (int*)p;  p += NUM_CLASS * 4;
    int* bases  = (int*)p;  p += NUM_CLASS * 4;

    prep_bucket_kernel<<<PREP_BLOCKS + 1, 256, 0, stream>>>(
        x, E, h, W, U, Vw, z, G, Bcat, Vw_bf, perm, counts, bases);
    rnn_gemm_kernel<<<dim3(BATCH / 32, NUM_CLASS), 256, 0, stream>>>(
        G, Bcat, perm, counts, bases, ht_out, ht_bf);
    out_gemm_kernel<<<4000, 256, 0, stream>>>(ht_bf, Vw_bf, Vb, logits);
}